// Round 18
// baseline (54.890 us; speedup 1.0000x reference)
//
#include <hip/hip_runtime.h>
#include <hip/hip_bf16.h>
#include <math.h>

#define B 4
#define T 4096
#define C 1024
#define HS 64

typedef __attribute__((ext_vector_type(8))) short short8;
typedef __attribute__((ext_vector_type(4))) float f32x4;
typedef __attribute__((ext_vector_type(16))) float f32x16;

#define MFMA16(a, b, c) __builtin_amdgcn_mfma_f32_16x16x32_bf16((a), (b), (c), 0, 0, 0)
#define MFMA32(a, b, c) __builtin_amdgcn_mfma_f32_32x32x16_bf16((a), (b), (c), 0, 0, 0)

// Q pre-scale: C^-0.5 * log2(e)  (softmax computed in 2^x domain)
#define QSCALE 0.0450842200278f

static __device__ __forceinline__ unsigned short f2bf(float f) {
  union { float f; unsigned u; } v; v.f = f;
  unsigned r = v.u + 0x7FFFu + ((v.u >> 16) & 1u);  // RNE to bf16
  return (unsigned short)(r >> 16);
}

static __device__ __forceinline__ unsigned pack_bf2(float lo, float hi2) {
  union { __hip_bfloat16 h; unsigned short u; } a, c;
  a.h = __float2bfloat16(lo); c.h = __float2bfloat16(hi2);
  return (unsigned)a.u | ((unsigned)c.u << 16);
}

// ---------------------------------------------------------------------------
// Kernel 0: W -> bf16 FRAGMENT-READY Wtf (round-17, verified).
// ---------------------------------------------------------------------------
__global__ __launch_bounds__(256) void conv_w_kernel(
    const float* __restrict__ Wq, const float* __restrict__ Wk,
    const float* __restrict__ Wv, unsigned short* __restrict__ Wtf) {
  const int wi = blockIdx.x >> 4;          // 0..2
  const int c0 = (blockIdx.x & 15) * 64;
  const float* W = (wi == 0) ? Wq : (wi == 1) ? Wk : Wv;
  __shared__ float ws[64][65];
  const int t = threadIdx.x;
  const int r = t >> 2;                    // c-row within chunk
  const int cb = (t & 3) * 16;             // h-col base
#pragma unroll
  for (int j = 0; j < 4; ++j) {
    const f32x4 v = *(const f32x4*)&W[(size_t)(c0 + r) * HS + cb + 4 * j];
    ws[cb + 4 * j + 0][r] = v[0];
    ws[cb + 4 * j + 1][r] = v[1];
    ws[cb + 4 * j + 2][r] = v[2];
    ws[cb + 4 * j + 3][r] = v[3];
  }
  __syncthreads();
  const int h  = t >> 2;                   // n within this W (0..63)
  const int rb = (t & 3) * 16;             // c base within chunk
  const int n   = wi * 64 + h;
  const int nt  = n >> 4;
  const int col = n & 15;
#pragma unroll
  for (int j = 0; j < 2; ++j) {
    const int cbase = c0 + rb + j * 8;     // 8-aligned
    union { short8 s8; unsigned short u[8]; } o;
#pragma unroll
    for (int e = 0; e < 8; ++e) o.u[e] = f2bf(ws[h][rb + j * 8 + e]);
    const int kc128 = cbase >> 7;
    const int k32   = (cbase >> 5) & 3;
    const int grp   = (cbase >> 3) & 3;
    const size_t idx =
        ((size_t)(kc128 * 48 + k32 * 12 + nt) * 512 + (grp * 16 + col) * 8);
    *(short8*)(Wtf + idx) = o.s8;
  }
}

// ---------------------------------------------------------------------------
// Kernel 1: fused QKV projection GEMM, v6: BK=64, LDS 64 KB -> 2 blocks/CU
// (barrier drains overlap with the co-resident block's compute), with the
// round-17 coalesced Wtf staging (1KB burst per fragment).
// ---------------------------------------------------------------------------
__global__ __launch_bounds__(512, 4) void proj_kernel(
    const float* __restrict__ x, const unsigned short* __restrict__ Wtf,
    const float* __restrict__ bq, const float* __restrict__ bk,
    const float* __restrict__ bv,
    unsigned short* __restrict__ Qf, unsigned short* __restrict__ Kf,
    unsigned short* __restrict__ Vf) {
  const int m0   = blockIdx.x * 64;
  const int w    = threadIdx.x >> 6;   // 0..7
  const int lane = threadIdx.x & 63;
  const int col  = lane & 15, grp = lane >> 4;
  const int wm   = w >> 2;             // 0..1: row half (32 rows)
  const int wn   = w & 3;              // 0..3: col group (48 cols)
  const int phase = blockIdx.x & 15;

  __shared__ unsigned short A_lds[2][64 * 64];    // 16 KB, XOR-swizzled rows
  __shared__ unsigned short B_lds[2][24][512];    // 48 KB, frag-ordered

  // A global: thread t loads row t>>3, 8 floats at (t&7)*8
  const int arow  = threadIdx.x >> 3;
  const int acol8 = threadIdx.x & 7;
  const float* xp = x + (size_t)(m0 + arow) * C + acol8 * 8;

  f32x4 acc[2][3];
#pragma unroll
  for (int mf = 0; mf < 2; ++mf)
#pragma unroll
    for (int jj = 0; jj < 3; ++jj) acc[mf][jj] = (f32x4){0.f, 0.f, 0.f, 0.f};

  auto kcOf = [&](int it) { return ((it + phase) & 15) * 64; };

  // stage this wave's 3 of the 24 B-fragments: contiguous 1KB per fragment
  auto stageB = [&](int nb, int kc) {
    const int kc128 = kc >> 7;
    const int k32b  = (kc >> 5) & 3;       // 0 or 2
#pragma unroll
    for (int j = 0; j < 3; ++j) {
      const int fl  = w * 3 + j;           // 0..23
      const int nt  = fl % 12;
      const int k32 = k32b + fl / 12;
      const unsigned short* src =
          Wtf + ((size_t)(kc128 * 48 + k32 * 12 + nt) * 512) + lane * 8;
      __builtin_amdgcn_global_load_lds(
          (const __attribute__((address_space(1))) void*)src,
          (__attribute__((address_space(3))) void*)&B_lds[nb][fl][0],
          16, 0, 0);
    }
  };

  auto loadAreg = [&](int kc, f32x4& r0, f32x4& r1) {
    r0 = *(const f32x4*)(xp + kc);
    r1 = *(const f32x4*)(xp + kc + 4);
  };

  auto writeA = [&](int nb, const f32x4& r0, const f32x4& r1) {
    union { short8 s8; unsigned short u[8]; } o;
#pragma unroll
    for (int e = 0; e < 4; ++e) {
      o.u[e] = f2bf(r0[e]);
      o.u[4 + e] = f2bf(r1[e]);
    }
    const int b0 = arow * 128 + acol8 * 16;     // byte offset (128B rows)
    const int s  = (arow & 7) << 4;             // XOR swizzle
    *(short8*)((char*)&A_lds[nb][0] + (b0 ^ s)) = o.s8;
  };

  auto readA = [&](int buf, int mf, int k32) {
    const int row = wm * 32 + mf * 16 + col;    // row&7 == col&7
    const int b = row * 128 + ((k32 * 64 + grp * 16) ^ ((col & 7) << 4));
    return *(const short8*)((const char*)&A_lds[buf][0] + b);
  };

  auto compute = [&](int buf) {
#pragma unroll
    for (int k32 = 0; k32 < 2; ++k32) {
      const short8 a0 = readA(buf, 0, k32);
      const short8 a1 = readA(buf, 1, k32);
#pragma unroll
      for (int jj = 0; jj < 3; ++jj) {
        const short8 bf =
            *(const short8*)&B_lds[buf][k32 * 12 + wn * 3 + jj][(size_t)lane * 8];
        acc[0][jj] = MFMA16(a0, bf, acc[0][jj]);
        acc[1][jj] = MFMA16(a1, bf, acc[1][jj]);
      }
    }
  };

  f32x4 aR0, aR1;
  loadAreg(kcOf(0), aR0, aR1);
  stageB(0, kcOf(0));
  writeA(0, aR0, aR1);
  loadAreg(kcOf(1), aR0, aR1);
  __syncthreads();

  for (int it = 0; it < 16; ++it) {
    const int buf = it & 1;
    if (it < 15) stageB(buf ^ 1, kcOf(it + 1));
    compute(buf);
    if (it < 15) {
      writeA(buf ^ 1, aR0, aR1);
      if (it < 14) loadAreg(kcOf(it + 2), aR0, aR1);
    }
    __syncthreads();
  }

  // ---- epilogue: bias/scale, write fragment-ready layouts ----
  auto writeOut = [&](int row, int n, float v) {
    const int bb  = row >> 12;          // batch (T = 4096)
    const int t   = row & (T - 1);
    const int blk = t >> 5;             // 32-row block
    const int r   = t & 31;
    if (n < 64) {
      const int j = n >> 4, h2 = (n >> 3) & 1, e = n & 7;
      Qf[((((size_t)bb * 128 + blk) * 4 + j) * 64 + h2 * 32 + r) * 8 + e] =
          f2bf(v * QSCALE);
    } else if (n < 128) {
      const int d = n - 64;
      const int f = d >> 4, h2 = (d >> 3) & 1, e = d & 7;
      Kf[((((size_t)bb * 128 + blk) * 4 + f) * 64 + h2 * 32 + r) * 8 + e] =
          f2bf(v);
    } else {
      const int d = n - 128;
      const int e = r & 7, h2 = (r >> 3) & 1, half = (r >> 4) & 1;
      const int vi = ((d >> 5) << 1) + half;
      const int q = d & 31;
      Vf[((((size_t)bb * 128 + blk) * 4 + vi) * 64 + h2 * 32 + q) * 8 + e] =
          f2bf(v);
    }
  };
#pragma unroll
  for (int mf = 0; mf < 2; ++mf) {
#pragma unroll
    for (int jj = 0; jj < 3; ++jj) {
      const int n = wn * 48 + jj * 16 + col;
      const float bias = (n < 64) ? bq[n] : (n < 128) ? bk[n - 64] : bv[n - 128];
#pragma unroll
      for (int r = 0; r < 4; ++r)
        writeOut(m0 + wm * 32 + mf * 16 + 4 * grp + r, n, acc[mf][jj][r] + bias);
    }
  }
}

// ---------------------------------------------------------------------------
// Kernel 2: flash attention, far-pair with ADAPTIVE wave split.
// Block p: near tile p gets w0 = round(8*(p+1)/129) waves, far tile 127-p
// gets 8-w0 -> every block's makespan ~ ceil(129/8) steps (was 32 at p=0).
// Step math byte-identical to R15 (fixed-offset exp2 softmax, K+V prefetch).
// Epilogue halves static: threads 0-255 -> tile p, 256-511 -> tile 127-p.
// ---------------------------------------------------------------------------
__global__ __launch_bounds__(512, 2) void attn_kernel(
    const unsigned short* __restrict__ Qf,
    const unsigned short* __restrict__ Kf,
    const unsigned short* __restrict__ Vf,
    float* __restrict__ out) {
  const int x8 = blockIdx.x & 7;
  const int b  = x8 >> 1;
  const int p  = ((blockIdx.x >> 3) << 1) | (x8 & 1);   // 0..63

  const int w8   = threadIdx.x >> 6;   // 0..7
  const int n0   = p + 1;
  int w0 = (8 * n0 + 64) / 129;        // rounded proportional split
  if (w0 < 1) w0 = 1;
  if (w0 > 7) w0 = 7;
  const int g    = (w8 >= w0) ? 1 : 0;
  const int lw   = g ? (w8 - w0) : w8; // local wave index in group
  const int nw   = g ? (8 - w0) : w0;  // group wave count (kb stride)
  const int lane = threadIdx.x & 63;
  const int q    = lane & 31;
  const int hi   = lane >> 5;          // 0..1
  const int qt   = g ? (127 - p) : p;  // this wave's q-tile
  const int qbase = qt * 32;
  const int qg    = qbase + q;

  __shared__ float accL[8][64][33];    // 67.6 KB
  __shared__ float lL[8][32], invL[2][32];

  const unsigned short* Qp = Qf + ((size_t)(b * 128 + qt) * 4) * 512;
  const unsigned short* Kb = Kf + ((size_t)b * 128) * 4 * 512;
  const unsigned short* Vb = Vf + ((size_t)b * 128) * 4 * 512;

  short8 qf[4];
#pragma unroll
  for (int j = 0; j < 4; ++j)
    qf[j] = *(const short8*)(Qp + j * 512 + lane * 8);

  f32x16 acc0, acc1;
#pragma unroll
  for (int r = 0; r < 16; ++r) { acc0[r] = 0.f; acc1[r] = 0.f; }
  float lsum = 0.f;

  const int nkv = qt + 1;

  short8 kA[4], vA[4], kB[4], vB[4];

  auto loadKV = [&](int kb, short8 (&kd)[4], short8 (&vd)[4]) {
    const unsigned short* pk = Kb + (size_t)kb * 2048 + lane * 8;
    kd[0] = *(const short8*)(pk);
    kd[1] = *(const short8*)(pk + 512);
    kd[2] = *(const short8*)(pk + 1024);
    kd[3] = *(const short8*)(pk + 1536);
    const unsigned short* pv = Vb + (size_t)kb * 2048 + lane * 8;
    vd[0] = *(const short8*)(pv);
    vd[1] = *(const short8*)(pv + 512);
    vd[2] = *(const short8*)(pv + 1024);
    vd[3] = *(const short8*)(pv + 1536);
  };

  auto step = [&](int kb, short8 (&kc)[4], short8 (&vc)[4],
                  short8 (&kn)[4], short8 (&vn)[4]) {
    int knb = kb + nw;                 // this wave's next kb (group stride)
    if (knb > 127) knb = 127;
    loadKV(knb, kn, vn);

    f32x16 s;
#pragma unroll
    for (int r = 0; r < 16; ++r) s[r] = -8.0f;
    s = MFMA32(kc[0], qf[0], s);
    s = MFMA32(kc[1], qf[1], s);
    s = MFMA32(kc[2], qf[2], s);
    s = MFMA32(kc[3], qf[3], s);

    float pe[16];
    if (kb == qt) {                    // diagonal block: causal mask
      const int qrel = qg - kb * 32;
#pragma unroll
      for (int r = 0; r < 16; ++r) {
        const int key = (r & 3) + 8 * (r >> 2) + 4 * hi;
        const float v = exp2f(s[r]);
        pe[r] = (key <= qrel) ? v : 0.f;
      }
    } else {
#pragma unroll
      for (int r = 0; r < 16; ++r) pe[r] = exp2f(s[r]);
    }
#pragma unroll
    for (int r = 0; r < 16; ++r) lsum += pe[r];

    unsigned own[8], oth[8];
#pragma unroll
    for (int j = 0; j < 8; ++j) own[j] = pack_bf2(pe[2 * j], pe[2 * j + 1]);
#pragma unroll
    for (int j = 0; j < 8; ++j) oth[j] = __shfl_xor(own[j], 32, 64);
    union U { short8 s8; unsigned u[4]; };
    U p0, p1;
    p0.u[0] = hi ? oth[2] : own[0];
    p0.u[1] = hi ? oth[3] : own[1];
    p0.u[2] = hi ? own[2] : oth[0];
    p0.u[3] = hi ? own[3] : oth[1];
    p1.u[0] = hi ? oth[6] : own[4];
    p1.u[1] = hi ? oth[7] : own[5];
    p1.u[2] = hi ? own[6] : oth[4];
    p1.u[3] = hi ? own[7] : oth[5];

    acc0 = MFMA32(vc[0], p0.s8, acc0);
    acc0 = MFMA32(vc[1], p1.s8, acc0);
    acc1 = MFMA32(vc[2], p0.s8, acc1);
    acc1 = MFMA32(vc[3], p1.s8, acc1);
  };

  if (lw < nkv) {
    loadKV(lw, kA, vA);
    int kb = lw;
    while (true) {
      step(kb, kA, vA, kB, vB); kb += nw; if (kb >= nkv) break;
      step(kb, kB, vB, kA, vA); kb += nw; if (kb >= nkv) break;
    }
  }

  // ---- per-group merge: plain sums (fixed offset -> no exp weights) ----
  lsum += __shfl_xor(lsum, 32, 64);    // combine the two key-halves
  if (hi == 0) lL[w8][q] = lsum;       // idle wave: 0
#pragma unroll
  for (int r = 0; r < 16; ++r) {
    const int d = (r & 3) + 8 * (r >> 2) + 4 * hi;
    accL[w8][d][q]      = acc0[r];
    accL[w8][d + 32][q] = acc1[r];
  }
  __syncthreads();
  if (threadIdx.x < 64) {
    const int g2 = threadIdx.x >> 5;
    const int qq = threadIdx.x & 31;
    const int lo = g2 ? w0 : 0, hiW = g2 ? 8 : w0;
    float L = 0.f;
    for (int ww = lo; ww < hiW; ++ww) L += lL[ww][qq];
    invL[g2][qq] = 1.f / L;            // L > 0: diagonal key always live
  }
  __syncthreads();
  {
    const int ge   = threadIdx.x >> 8;           // epilogue half: 0 or 1
    const int tid2 = threadIdx.x & 255;
    const int qbE  = (ge ? (127 - p) : p) * 32;
    const int lo = ge ? w0 : 0, hiW = ge ? 8 : w0;
#pragma unroll
    for (int pp = 0; pp < 8; ++pp) {
      const int qq = (tid2 >> 6) + 4 * pp;
      const int d  = tid2 & 63;
      float v = 0.f;
      for (int ww = lo; ww < hiW; ++ww) v += accL[ww][d][qq];
      out[(size_t)(b * T + qbE + qq) * HS + d] = v * invL[ge][qq];
    }
  }
}

extern "C" void kernel_launch(void* const* d_in, const int* in_sizes, int n_in,
                              void* d_out, int out_size, void* d_ws, size_t ws_size,
                              hipStream_t stream) {
  const float* x  = (const float*)d_in[0];
  const float* Wq = (const float*)d_in[1];
  const float* bq = (const float*)d_in[2];
  const float* Wk = (const float*)d_in[3];
  const float* bk = (const float*)d_in[4];
  const float* Wv = (const float*)d_in[5];
  const float* bv = (const float*)d_in[6];
  float* out = (float*)d_out;

  unsigned short* Qf  = (unsigned short*)d_ws;
  unsigned short* Kf  = Qf + (size_t)B * T * HS;
  unsigned short* Vf  = Kf + (size_t)B * T * HS;
  unsigned short* Wtf = Vf + (size_t)B * T * HS;

  conv_w_kernel<<<48, 256, 0, stream>>>(Wq, Wk, Wv, Wtf);
  proj_kernel<<<B * T / 64, 512, 0, stream>>>(x, Wtf, bq, bk, bv, Qf, Kf, Vf);
  attn_kernel<<<B * 64, 512, 0, stream>>>(Qf, Kf, Vf, out);
}

// Round 19
// 50.022 us; speedup vs baseline: 1.0973x; 1.0973x over previous
//
#include <hip/hip_runtime.h>
#include <hip/hip_bf16.h>
#include <math.h>

#define B 4
#define T 4096
#define C 1024
#define HS 64

typedef __attribute__((ext_vector_type(8))) short short8;
typedef __attribute__((ext_vector_type(4))) float f32x4;
typedef __attribute__((ext_vector_type(16))) float f32x16;

#define MFMA16(a, b, c) __builtin_amdgcn_mfma_f32_16x16x32_bf16((a), (b), (c), 0, 0, 0)
#define MFMA32(a, b, c) __builtin_amdgcn_mfma_f32_32x32x16_bf16((a), (b), (c), 0, 0, 0)

// Q pre-scale: C^-0.5 * log2(e)  (softmax computed in 2^x domain)
#define QSCALE 0.0450842200278f

static __device__ __forceinline__ unsigned short f2bf(float f) {
  union { float f; unsigned u; } v; v.f = f;
  unsigned r = v.u + 0x7FFFu + ((v.u >> 16) & 1u);  // RNE to bf16
  return (unsigned short)(r >> 16);
}

static __device__ __forceinline__ unsigned pack_bf2(float lo, float hi2) {
  union { __hip_bfloat16 h; unsigned short u; } a, c;
  a.h = __float2bfloat16(lo); c.h = __float2bfloat16(hi2);
  return (unsigned)a.u | ((unsigned)c.u << 16);
}

// ---------------------------------------------------------------------------
// Kernel 0: W -> bf16 FRAGMENT-READY Wtf (round-17, verified).
// ---------------------------------------------------------------------------
__global__ __launch_bounds__(256) void conv_w_kernel(
    const float* __restrict__ Wq, const float* __restrict__ Wk,
    const float* __restrict__ Wv, unsigned short* __restrict__ Wtf) {
  const int wi = blockIdx.x >> 4;          // 0..2
  const int c0 = (blockIdx.x & 15) * 64;
  const float* W = (wi == 0) ? Wq : (wi == 1) ? Wk : Wv;
  __shared__ float ws[64][65];
  const int t = threadIdx.x;
  const int r = t >> 2;                    // c-row within chunk
  const int cb = (t & 3) * 16;             // h-col base
#pragma unroll
  for (int j = 0; j < 4; ++j) {
    const f32x4 v = *(const f32x4*)&W[(size_t)(c0 + r) * HS + cb + 4 * j];
    ws[cb + 4 * j + 0][r] = v[0];
    ws[cb + 4 * j + 1][r] = v[1];
    ws[cb + 4 * j + 2][r] = v[2];
    ws[cb + 4 * j + 3][r] = v[3];
  }
  __syncthreads();
  const int h  = t >> 2;                   // n within this W (0..63)
  const int rb = (t & 3) * 16;             // c base within chunk
  const int n   = wi * 64 + h;
  const int nt  = n >> 4;
  const int col = n & 15;
#pragma unroll
  for (int j = 0; j < 2; ++j) {
    const int cbase = c0 + rb + j * 8;     // 8-aligned
    union { short8 s8; unsigned short u[8]; } o;
#pragma unroll
    for (int e = 0; e < 8; ++e) o.u[e] = f2bf(ws[h][rb + j * 8 + e]);
    const int kc128 = cbase >> 7;
    const int k32   = (cbase >> 5) & 3;
    const int grp   = (cbase >> 3) & 3;
    const size_t idx =
        ((size_t)(kc128 * 48 + k32 * 12 + nt) * 512 + (grp * 16 + col) * 8);
    *(short8*)(Wtf + idx) = o.s8;
  }
}

// ---------------------------------------------------------------------------
// Kernel 1: fused QKV projection GEMM — round-17 (BK=128, 8 iters, coalesced
// Wtf staging; verified best).
// ---------------------------------------------------------------------------
__global__ __launch_bounds__(512, 2) void proj_kernel(
    const float* __restrict__ x, const unsigned short* __restrict__ Wtf,
    const float* __restrict__ bq, const float* __restrict__ bk,
    const float* __restrict__ bv,
    unsigned short* __restrict__ Qf, unsigned short* __restrict__ Kf,
    unsigned short* __restrict__ Vf) {
  const int m0   = blockIdx.x * 64;
  const int w    = threadIdx.x >> 6;   // 0..7
  const int lane = threadIdx.x & 63;
  const int col  = lane & 15, grp = lane >> 4;
  const int wm   = w >> 2;             // 0..1: row half (32 rows)
  const int wn   = w & 3;              // 0..3: col group (48 cols)
  const int phase = blockIdx.x & 7;

  __shared__ unsigned short A_lds[2][64 * 128];   // 32 KB, XOR-swizzled rows
  __shared__ unsigned short B_lds[2][48][512];    // 96 KB, frag-ordered

  const int arow  = threadIdx.x >> 3;
  const int akoff = (threadIdx.x & 7) * 16;
  const float* xp = x + (size_t)(m0 + arow) * C + akoff;

  f32x4 acc[2][3];
#pragma unroll
  for (int mf = 0; mf < 2; ++mf)
#pragma unroll
    for (int jj = 0; jj < 3; ++jj) acc[mf][jj] = (f32x4){0.f, 0.f, 0.f, 0.f};

  auto kcOf = [&](int it) { return ((it + phase) & 7) * 128; };

  // stage this wave's 6 of the 48 B-fragments: contiguous 1KB per fragment
  auto stageB = [&](int nb, int kc) {
    const int kc128 = kc >> 7;
#pragma unroll
    for (int j = 0; j < 6; ++j) {
      const int f = w * 6 + j;
      const unsigned short* src =
          Wtf + ((size_t)(kc128 * 48 + f) * 512) + lane * 8;
      __builtin_amdgcn_global_load_lds(
          (const __attribute__((address_space(1))) void*)src,
          (__attribute__((address_space(3))) void*)&B_lds[nb][f][0],
          16, 0, 0);
    }
  };

  auto loadAreg = [&](int kc, f32x4 (&r)[4]) {
#pragma unroll
    for (int i = 0; i < 4; ++i) r[i] = *(const f32x4*)(xp + kc + 4 * i);
  };

  auto writeA = [&](int nb, const f32x4 (&r)[4]) {
    union { short8 s8[2]; unsigned short u[16]; } o;
#pragma unroll
    for (int i = 0; i < 4; ++i)
#pragma unroll
      for (int e = 0; e < 4; ++e) o.u[4 * i + e] = f2bf(r[i][e]);
    const int b0 = arow * 256 + (threadIdx.x & 7) * 32;   // byte offset
    const int s  = (arow & 7) << 4;                        // XOR swizzle
    char* base = (char*)&A_lds[nb][0];
    *(short8*)(base + ((b0     ) ^ s)) = o.s8[0];
    *(short8*)(base + ((b0 + 16) ^ s)) = o.s8[1];
  };

  auto readA = [&](int buf, int mf, int k32) {
    const int row = wm * 32 + mf * 16 + col;
    const int b = row * 256 + ((k32 * 64 + grp * 16) ^ ((col & 7) << 4));
    return *(const short8*)((const char*)&A_lds[buf][0] + b);
  };

  auto compute = [&](int buf) {
#pragma unroll
    for (int k32 = 0; k32 < 4; ++k32) {
      const short8 a0 = readA(buf, 0, k32);
      const short8 a1 = readA(buf, 1, k32);
#pragma unroll
      for (int jj = 0; jj < 3; ++jj) {
        const short8 bf =
            *(const short8*)&B_lds[buf][k32 * 12 + wn * 3 + jj][(size_t)lane * 8];
        acc[0][jj] = MFMA16(a0, bf, acc[0][jj]);
        acc[1][jj] = MFMA16(a1, bf, acc[1][jj]);
      }
    }
  };

  f32x4 arA[4];
  loadAreg(kcOf(0), arA);
  stageB(0, kcOf(0));
  writeA(0, arA);
  loadAreg(kcOf(1), arA);
  __syncthreads();

  for (int it = 0; it < 8; ++it) {
    const int buf = it & 1;
    if (it < 7) stageB(buf ^ 1, kcOf(it + 1));
    compute(buf);
    if (it < 7) {
      writeA(buf ^ 1, arA);
      if (it < 6) loadAreg(kcOf(it + 2), arA);
    }
    __syncthreads();
  }

  // ---- epilogue: bias/scale, write fragment-ready layouts ----
  auto writeOut = [&](int row, int n, float v) {
    const int bb  = row >> 12;          // batch (T = 4096)
    const int t   = row & (T - 1);
    const int blk = t >> 5;             // 32-row block
    const int r   = t & 31;
    if (n < 64) {
      const int j = n >> 4, h2 = (n >> 3) & 1, e = n & 7;
      Qf[((((size_t)bb * 128 + blk) * 4 + j) * 64 + h2 * 32 + r) * 8 + e] =
          f2bf(v * QSCALE);
    } else if (n < 128) {
      const int d = n - 64;
      const int f = d >> 4, h2 = (d >> 3) & 1, e = d & 7;
      Kf[((((size_t)bb * 128 + blk) * 4 + f) * 64 + h2 * 32 + r) * 8 + e] =
          f2bf(v);
    } else {
      const int d = n - 128;
      const int e = r & 7, h2 = (r >> 3) & 1, half = (r >> 4) & 1;
      const int vi = ((d >> 5) << 1) + half;
      const int q = d & 31;
      Vf[((((size_t)bb * 128 + blk) * 4 + vi) * 64 + h2 * 32 + q) * 8 + e] =
          f2bf(v);
    }
  };
#pragma unroll
  for (int mf = 0; mf < 2; ++mf) {
#pragma unroll
    for (int jj = 0; jj < 3; ++jj) {
      const int n = wn * 48 + jj * 16 + col;
      const float bias = (n < 64) ? bq[n] : (n < 128) ? bk[n - 64] : bv[n - 128];
#pragma unroll
      for (int r = 0; r < 4; ++r)
        writeOut(m0 + wm * 32 + mf * 16 + 4 * grp + r, n, acc[mf][jj][r] + bias);
    }
  }
}

// ---------------------------------------------------------------------------
// Kernel 2: flash attention, far-pair (R15 structure) with the lane-half
// exchange done via v_permlane32_swap_b32: swap(own[0],own[2]) yields BOTH
// p0.u[0] = {own0.lo, own2-from-lo} and p0.u[2] = {own0-from-hi, own2.hi}
// — 4 swaps replace 8 ds_permute + 8 selects (off the LDS pipe entirely).
// ---------------------------------------------------------------------------
__global__ __launch_bounds__(512, 2) void attn_kernel(
    const unsigned short* __restrict__ Qf,
    const unsigned short* __restrict__ Kf,
    const unsigned short* __restrict__ Vf,
    float* __restrict__ out) {
  const int x8 = blockIdx.x & 7;
  const int b  = x8 >> 1;
  const int p  = ((blockIdx.x >> 3) << 1) | (x8 & 1);   // 0..63

  const int w8   = threadIdx.x >> 6;   // 0..7
  const int g    = w8 >> 2;            // group 0/1
  const int w    = w8 & 3;             // wave within group
  const int lane = threadIdx.x & 63;
  const int q    = lane & 31;
  const int hi   = lane >> 5;          // 0..1
  const int qt   = g ? (127 - p) : p;  // this group's q-tile
  const int qbase = qt * 32;
  const int qg    = qbase + q;

  __shared__ float accL[8][64][33];    // 67.6 KB
  __shared__ float lL[8][32], invL[2][32];

  const unsigned short* Qp = Qf + ((size_t)(b * 128 + qt) * 4) * 512;
  const unsigned short* Kb = Kf + ((size_t)b * 128) * 4 * 512;
  const unsigned short* Vb = Vf + ((size_t)b * 128) * 4 * 512;

  short8 qf[4];
#pragma unroll
  for (int j = 0; j < 4; ++j)
    qf[j] = *(const short8*)(Qp + j * 512 + lane * 8);

  f32x16 acc0, acc1;
#pragma unroll
  for (int r = 0; r < 16; ++r) { acc0[r] = 0.f; acc1[r] = 0.f; }
  float lsum = 0.f;

  const int nkv = qt + 1;

  short8 kA[4], vA[4], kB[4], vB[4];

  auto loadKV = [&](int kb, short8 (&kd)[4], short8 (&vd)[4]) {
    const unsigned short* pk = Kb + (size_t)kb * 2048 + lane * 8;
    kd[0] = *(const short8*)(pk);
    kd[1] = *(const short8*)(pk + 512);
    kd[2] = *(const short8*)(pk + 1024);
    kd[3] = *(const short8*)(pk + 1536);
    const unsigned short* pv = Vb + (size_t)kb * 2048 + lane * 8;
    vd[0] = *(const short8*)(pv);
    vd[1] = *(const short8*)(pv + 512);
    vd[2] = *(const short8*)(pv + 1024);
    vd[3] = *(const short8*)(pv + 1536);
  };

  auto step = [&](int kb, short8 (&kc)[4], short8 (&vc)[4],
                  short8 (&kn)[4], short8 (&vn)[4]) {
    int knb = kb + 4;                  // this wave's next kb
    if (knb > 127) knb = 127;
    loadKV(knb, kn, vn);

    // QK^T with the softmax offset folded into the accumulator init:
    // s = Q.K - 8  (scores |Q.K| <~ 3, so P = 2^s is bf16-safe)
    f32x16 s;
#pragma unroll
    for (int r = 0; r < 16; ++r) s[r] = -8.0f;
    s = MFMA32(kc[0], qf[0], s);
    s = MFMA32(kc[1], qf[1], s);
    s = MFMA32(kc[2], qf[2], s);
    s = MFMA32(kc[3], qf[3], s);

    float pe[16];
    if (kb == qt) {                    // diagonal block: causal mask
      const int qrel = qg - kb * 32;
#pragma unroll
      for (int r = 0; r < 16; ++r) {
        const int key = (r & 3) + 8 * (r >> 2) + 4 * hi;
        const float v = exp2f(s[r]);
        pe[r] = (key <= qrel) ? v : 0.f;
      }
    } else {
#pragma unroll
      for (int r = 0; r < 16; ++r) pe[r] = exp2f(s[r]);
    }
#pragma unroll
    for (int r = 0; r < 16; ++r) lsum += pe[r];

    unsigned own[8];
#pragma unroll
    for (int j = 0; j < 8; ++j) own[j] = pack_bf2(pe[2 * j], pe[2 * j + 1]);
    // lane-half exchange: one swap produces both needed fragments.
    unsigned a0v = own[0], b0v = own[2];
    unsigned a1v = own[1], b1v = own[3];
    unsigned a2v = own[4], b2v = own[6];
    unsigned a3v = own[5], b3v = own[7];
    asm("v_permlane32_swap_b32 %0, %1" : "+v"(a0v), "+v"(b0v));
    asm("v_permlane32_swap_b32 %0, %1" : "+v"(a1v), "+v"(b1v));
    asm("v_permlane32_swap_b32 %0, %1" : "+v"(a2v), "+v"(b2v));
    asm("v_permlane32_swap_b32 %0, %1" : "+v"(a3v), "+v"(b3v));
    union U { short8 s8; unsigned u[4]; };
    U p0, p1;
    p0.u[0] = a0v; p0.u[1] = a1v; p0.u[2] = b0v; p0.u[3] = b1v;
    p1.u[0] = a2v; p1.u[1] = a3v; p1.u[2] = b2v; p1.u[3] = b3v;

    acc0 = MFMA32(vc[0], p0.s8, acc0);
    acc0 = MFMA32(vc[1], p1.s8, acc0);
    acc1 = MFMA32(vc[2], p0.s8, acc1);
    acc1 = MFMA32(vc[3], p1.s8, acc1);
  };

  if (w < nkv) {
    loadKV(w, kA, vA);
    int kb = w;
    while (true) {
      step(kb, kA, vA, kB, vB); kb += 4; if (kb >= nkv) break;
      step(kb, kB, vB, kA, vA); kb += 4; if (kb >= nkv) break;
    }
  }

  // ---- per-group merge: plain sums (fixed offset -> no exp weights) ----
  lsum += __shfl_xor(lsum, 32, 64);    // combine the two key-halves
  if (hi == 0) lL[w8][q] = lsum;       // idle wave: 0
#pragma unroll
  for (int r = 0; r < 16; ++r) {
    const int d = (r & 3) + 8 * (r >> 2) + 4 * hi;
    accL[w8][d][q]      = acc0[r];
    accL[w8][d + 32][q] = acc1[r];
  }
  __syncthreads();
  if (threadIdx.x < 64) {
    const int g2 = threadIdx.x >> 5;
    const int qq = threadIdx.x & 31;
    const float L = lL[g2 * 4 + 0][qq] + lL[g2 * 4 + 1][qq] +
                    lL[g2 * 4 + 2][qq] + lL[g2 * 4 + 3][qq];
    invL[g2][qq] = 1.f / L;            // L > 0: diagonal key always live
  }
  __syncthreads();
  {
    const int tid2 = threadIdx.x & 255;
#pragma unroll
    for (int pp = 0; pp < 8; ++pp) {
      const int qq = (tid2 >> 6) + 4 * pp;
      const int d  = tid2 & 63;
      const float v = accL[g * 4 + 0][d][qq] + accL[g * 4 + 1][d][qq] +
                      accL[g * 4 + 2][d][qq] + accL[g * 4 + 3][d][qq];
      out[(size_t)(b * T + qbase + qq) * HS + d] = v * invL[g][qq];
    }
  }
}

extern "C" void kernel_launch(void* const* d_in, const int* in_sizes, int n_in,
                              void* d_out, int out_size, void* d_ws, size_t ws_size,
                              hipStream_t stream) {
  const float* x  = (const float*)d_in[0];
  const float* Wq = (const float*)d_in[1];
  const float* bq = (const float*)d_in[2];
  const float* Wk = (const float*)d_in[3];
  const float* bk = (const float*)d_in[4];
  const float* Wv = (const float*)d_in[5];
  const float* bv = (const float*)d_in[6];
  float* out = (float*)d_out;

  unsigned short* Qf  = (unsigned short*)d_ws;
  unsigned short* Kf  = Qf + (size_t)B * T * HS;
  unsigned short* Vf  = Kf + (size_t)B * T * HS;
  unsigned short* Wtf = Vf + (size_t)B * T * HS;

  conv_w_kernel<<<48, 256, 0, stream>>>(Wq, Wk, Wv, Wtf);
  proj_kernel<<<B * T / 64, 512, 0, stream>>>(x, Wtf, bq, bk, bv, Qf, Kf, Vf);
  attn_kernel<<<B * 64, 512, 0, stream>>>(Qf, Kf, Vf, out);
}

// Round 20
// 49.502 us; speedup vs baseline: 1.1088x; 1.0105x over previous
//
#include <hip/hip_runtime.h>
#include <hip/hip_bf16.h>
#include <math.h>

#define B 4
#define T 4096
#define C 1024
#define HS 64

typedef __attribute__((ext_vector_type(8))) short short8;
typedef __attribute__((ext_vector_type(4))) float f32x4;
typedef __attribute__((ext_vector_type(16))) float f32x16;

#define MFMA16(a, b, c) __builtin_amdgcn_mfma_f32_16x16x32_bf16((a), (b), (c), 0, 0, 0)
#define MFMA32(a, b, c) __builtin_amdgcn_mfma_f32_32x32x16_bf16((a), (b), (c), 0, 0, 0)

// Q pre-scale: C^-0.5 * log2(e)  (softmax computed in 2^x domain)
#define QSCALE 0.0450842200278f

static __device__ __forceinline__ unsigned short f2bf(float f) {
  union { float f; unsigned u; } v; v.f = f;
  unsigned r = v.u + 0x7FFFu + ((v.u >> 16) & 1u);  // RNE to bf16
  return (unsigned short)(r >> 16);
}

static __device__ __forceinline__ unsigned pack_bf2(float lo, float hi2) {
  union { __hip_bfloat16 h; unsigned short u; } a, c;
  a.h = __float2bfloat16(lo); c.h = __float2bfloat16(hi2);
  return (unsigned)a.u | ((unsigned)c.u << 16);
}

// ---------------------------------------------------------------------------
// Kernel 0: W -> bf16 FRAGMENT-READY Wtf (round-17, verified).
// ---------------------------------------------------------------------------
__global__ __launch_bounds__(256) void conv_w_kernel(
    const float* __restrict__ Wq, const float* __restrict__ Wk,
    const float* __restrict__ Wv, unsigned short* __restrict__ Wtf) {
  const int wi = blockIdx.x >> 4;          // 0..2
  const int c0 = (blockIdx.x & 15) * 64;
  const float* W = (wi == 0) ? Wq : (wi == 1) ? Wk : Wv;
  __shared__ float ws[64][65];
  const int t = threadIdx.x;
  const int r = t >> 2;                    // c-row within chunk
  const int cb = (t & 3) * 16;             // h-col base
#pragma unroll
  for (int j = 0; j < 4; ++j) {
    const f32x4 v = *(const f32x4*)&W[(size_t)(c0 + r) * HS + cb + 4 * j];
    ws[cb + 4 * j + 0][r] = v[0];
    ws[cb + 4 * j + 1][r] = v[1];
    ws[cb + 4 * j + 2][r] = v[2];
    ws[cb + 4 * j + 3][r] = v[3];
  }
  __syncthreads();
  const int h  = t >> 2;                   // n within this W (0..63)
  const int rb = (t & 3) * 16;             // c base within chunk
  const int n   = wi * 64 + h;
  const int nt  = n >> 4;
  const int col = n & 15;
#pragma unroll
  for (int j = 0; j < 2; ++j) {
    const int cbase = c0 + rb + j * 8;     // 8-aligned
    union { short8 s8; unsigned short u[8]; } o;
#pragma unroll
    for (int e = 0; e < 8; ++e) o.u[e] = f2bf(ws[h][rb + j * 8 + e]);
    const int kc128 = cbase >> 7;
    const int k32   = (cbase >> 5) & 3;
    const int grp   = (cbase >> 3) & 3;
    const size_t idx =
        ((size_t)(kc128 * 48 + k32 * 12 + nt) * 512 + (grp * 16 + col) * 8);
    *(short8*)(Wtf + idx) = o.s8;
  }
}

// ---------------------------------------------------------------------------
// Kernel 1: fused QKV projection GEMM — round-17 core; epilogue now stages
// the 64x192 bf16 output tile through LDS (reusing A_lds) in the exact
// Qf/Kf/Vf fragment layouts, then stores 1KB coalesced bursts (was 24
// scattered 2B stores/thread -> ~25x fewer store transactions).
// ---------------------------------------------------------------------------
__global__ __launch_bounds__(512, 2) void proj_kernel(
    const float* __restrict__ x, const unsigned short* __restrict__ Wtf,
    const float* __restrict__ bq, const float* __restrict__ bk,
    const float* __restrict__ bv,
    unsigned short* __restrict__ Qf, unsigned short* __restrict__ Kf,
    unsigned short* __restrict__ Vf) {
  const int m0   = blockIdx.x * 64;
  const int w    = threadIdx.x >> 6;   // 0..7
  const int lane = threadIdx.x & 63;
  const int col  = lane & 15, grp = lane >> 4;
  const int wm   = w >> 2;             // 0..1: row half (32 rows)
  const int wn   = w & 3;              // 0..3: col group (48 cols)
  const int phase = blockIdx.x & 7;

  __shared__ unsigned short A_lds[2][64 * 128];   // 32 KB, XOR-swizzled rows
  __shared__ unsigned short B_lds[2][48][512];    // 96 KB, frag-ordered

  const int arow  = threadIdx.x >> 3;
  const int akoff = (threadIdx.x & 7) * 16;
  const float* xp = x + (size_t)(m0 + arow) * C + akoff;

  f32x4 acc[2][3];
#pragma unroll
  for (int mf = 0; mf < 2; ++mf)
#pragma unroll
    for (int jj = 0; jj < 3; ++jj) acc[mf][jj] = (f32x4){0.f, 0.f, 0.f, 0.f};

  auto kcOf = [&](int it) { return ((it + phase) & 7) * 128; };

  auto stageB = [&](int nb, int kc) {
    const int kc128 = kc >> 7;
#pragma unroll
    for (int j = 0; j < 6; ++j) {
      const int f = w * 6 + j;
      const unsigned short* src =
          Wtf + ((size_t)(kc128 * 48 + f) * 512) + lane * 8;
      __builtin_amdgcn_global_load_lds(
          (const __attribute__((address_space(1))) void*)src,
          (__attribute__((address_space(3))) void*)&B_lds[nb][f][0],
          16, 0, 0);
    }
  };

  auto loadAreg = [&](int kc, f32x4 (&r)[4]) {
#pragma unroll
    for (int i = 0; i < 4; ++i) r[i] = *(const f32x4*)(xp + kc + 4 * i);
  };

  auto writeA = [&](int nb, const f32x4 (&r)[4]) {
    union { short8 s8[2]; unsigned short u[16]; } o;
#pragma unroll
    for (int i = 0; i < 4; ++i)
#pragma unroll
      for (int e = 0; e < 4; ++e) o.u[4 * i + e] = f2bf(r[i][e]);
    const int b0 = arow * 256 + (threadIdx.x & 7) * 32;   // byte offset
    const int s  = (arow & 7) << 4;                        // XOR swizzle
    char* base = (char*)&A_lds[nb][0];
    *(short8*)(base + ((b0     ) ^ s)) = o.s8[0];
    *(short8*)(base + ((b0 + 16) ^ s)) = o.s8[1];
  };

  auto readA = [&](int buf, int mf, int k32) {
    const int row = wm * 32 + mf * 16 + col;
    const int b = row * 256 + ((k32 * 64 + grp * 16) ^ ((col & 7) << 4));
    return *(const short8*)((const char*)&A_lds[buf][0] + b);
  };

  auto compute = [&](int buf) {
#pragma unroll
    for (int k32 = 0; k32 < 4; ++k32) {
      const short8 a0 = readA(buf, 0, k32);
      const short8 a1 = readA(buf, 1, k32);
#pragma unroll
      for (int jj = 0; jj < 3; ++jj) {
        const short8 bf =
            *(const short8*)&B_lds[buf][k32 * 12 + wn * 3 + jj][(size_t)lane * 8];
        acc[0][jj] = MFMA16(a0, bf, acc[0][jj]);
        acc[1][jj] = MFMA16(a1, bf, acc[1][jj]);
      }
    }
  };

  f32x4 arA[4];
  loadAreg(kcOf(0), arA);
  stageB(0, kcOf(0));
  writeA(0, arA);
  loadAreg(kcOf(1), arA);
  __syncthreads();

  for (int it = 0; it < 8; ++it) {
    const int buf = it & 1;
    if (it < 7) stageB(buf ^ 1, kcOf(it + 1));
    compute(buf);
    if (it < 7) {
      writeA(buf ^ 1, arA);
      if (it < 6) loadAreg(kcOf(it + 2), arA);
    }
    __syncthreads();
  }

  // ---- epilogue v2: stage through LDS in fragment layout, store 1KB bursts
  // E[blk_local(2)][ftype(12)][512]: ftype 0-3 = Q j, 4-7 = K f, 8-11 = V vi.
  unsigned short (*E)[12][512] =
      (unsigned short (*)[12][512]) & A_lds[0][0];   // 24 KB reuse

#pragma unroll
  for (int mf = 0; mf < 2; ++mf) {
#pragma unroll
    for (int jj = 0; jj < 3; ++jj) {
      const int n = wn * 48 + jj * 16 + col;
      const float bias = (n < 64) ? bq[n] : (n < 128) ? bk[n - 64] : bv[n - 128];
#pragma unroll
      for (int r = 0; r < 4; ++r) {
        const int rloc = mf * 16 + 4 * grp + r;     // row within 32-row blk
        const float v = acc[mf][jj][r] + bias;      // blk_local = wm
        if (n < 64) {
          E[wm][n >> 4][(((n >> 3) & 1) * 32 + rloc) * 8 + (n & 7)] =
              f2bf(v * QSCALE);
        } else if (n < 128) {
          const int d = n - 64;
          E[wm][4 + (d >> 4)][(((d >> 3) & 1) * 32 + rloc) * 8 + (d & 7)] =
              f2bf(v);
        } else {
          const int d = n - 128;
          const int vi = ((d >> 5) << 1) + ((rloc >> 4) & 1);
          E[wm][8 + vi][(((rloc >> 3) & 1) * 32 + (d & 31)) * 8 + (rloc & 7)] =
              f2bf(v);
        }
      }
    }
  }
  __syncthreads();

  {
    const int bb    = m0 >> 12;
    const int blkg0 = (m0 & (T - 1)) >> 5;
#pragma unroll
    for (int j = 0; j < 3; ++j) {
      const int fidx  = w * 3 + j;        // 0..23
      const int blk_l = fidx / 12;
      const int ft    = fidx % 12;
      const short8 val = *(const short8*)&E[blk_l][ft][lane * 8];
      const size_t fb = ((size_t)(bb * 128 + blkg0 + blk_l) * 4);
      unsigned short* dst;
      if (ft < 4)      dst = Qf + (fb + ft) * 512;
      else if (ft < 8) dst = Kf + (fb + (ft - 4)) * 512;
      else             dst = Vf + (fb + (ft - 8)) * 512;
      *(short8*)(dst + lane * 8) = val;
    }
  }
}

// ---------------------------------------------------------------------------
// Kernel 2: flash attention, far-pair + permlane32_swap (byte-identical R19).
// ---------------------------------------------------------------------------
__global__ __launch_bounds__(512, 2) void attn_kernel(
    const unsigned short* __restrict__ Qf,
    const unsigned short* __restrict__ Kf,
    const unsigned short* __restrict__ Vf,
    float* __restrict__ out) {
  const int x8 = blockIdx.x & 7;
  const int b  = x8 >> 1;
  const int p  = ((blockIdx.x >> 3) << 1) | (x8 & 1);   // 0..63

  const int w8   = threadIdx.x >> 6;   // 0..7
  const int g    = w8 >> 2;            // group 0/1
  const int w    = w8 & 3;             // wave within group
  const int lane = threadIdx.x & 63;
  const int q    = lane & 31;
  const int hi   = lane >> 5;          // 0..1
  const int qt   = g ? (127 - p) : p;  // this group's q-tile
  const int qbase = qt * 32;
  const int qg    = qbase + q;

  __shared__ float accL[8][64][33];    // 67.6 KB
  __shared__ float lL[8][32], invL[2][32];

  const unsigned short* Qp = Qf + ((size_t)(b * 128 + qt) * 4) * 512;
  const unsigned short* Kb = Kf + ((size_t)b * 128) * 4 * 512;
  const unsigned short* Vb = Vf + ((size_t)b * 128) * 4 * 512;

  short8 qf[4];
#pragma unroll
  for (int j = 0; j < 4; ++j)
    qf[j] = *(const short8*)(Qp + j * 512 + lane * 8);

  f32x16 acc0, acc1;
#pragma unroll
  for (int r = 0; r < 16; ++r) { acc0[r] = 0.f; acc1[r] = 0.f; }
  float lsum = 0.f;

  const int nkv = qt + 1;

  short8 kA[4], vA[4], kB[4], vB[4];

  auto loadKV = [&](int kb, short8 (&kd)[4], short8 (&vd)[4]) {
    const unsigned short* pk = Kb + (size_t)kb * 2048 + lane * 8;
    kd[0] = *(const short8*)(pk);
    kd[1] = *(const short8*)(pk + 512);
    kd[2] = *(const short8*)(pk + 1024);
    kd[3] = *(const short8*)(pk + 1536);
    const unsigned short* pv = Vb + (size_t)kb * 2048 + lane * 8;
    vd[0] = *(const short8*)(pv);
    vd[1] = *(const short8*)(pv + 512);
    vd[2] = *(const short8*)(pv + 1024);
    vd[3] = *(const short8*)(pv + 1536);
  };

  auto step = [&](int kb, short8 (&kc)[4], short8 (&vc)[4],
                  short8 (&kn)[4], short8 (&vn)[4]) {
    int knb = kb + 4;                  // this wave's next kb
    if (knb > 127) knb = 127;
    loadKV(knb, kn, vn);

    f32x16 s;
#pragma unroll
    for (int r = 0; r < 16; ++r) s[r] = -8.0f;
    s = MFMA32(kc[0], qf[0], s);
    s = MFMA32(kc[1], qf[1], s);
    s = MFMA32(kc[2], qf[2], s);
    s = MFMA32(kc[3], qf[3], s);

    float pe[16];
    if (kb == qt) {                    // diagonal block: causal mask
      const int qrel = qg - kb * 32;
#pragma unroll
      for (int r = 0; r < 16; ++r) {
        const int key = (r & 3) + 8 * (r >> 2) + 4 * hi;
        const float v = exp2f(s[r]);
        pe[r] = (key <= qrel) ? v : 0.f;
      }
    } else {
#pragma unroll
      for (int r = 0; r < 16; ++r) pe[r] = exp2f(s[r]);
    }
#pragma unroll
    for (int r = 0; r < 16; ++r) lsum += pe[r];

    unsigned own[8];
#pragma unroll
    for (int j = 0; j < 8; ++j) own[j] = pack_bf2(pe[2 * j], pe[2 * j + 1]);
    unsigned a0v = own[0], b0v = own[2];
    unsigned a1v = own[1], b1v = own[3];
    unsigned a2v = own[4], b2v = own[6];
    unsigned a3v = own[5], b3v = own[7];
    asm("v_permlane32_swap_b32 %0, %1" : "+v"(a0v), "+v"(b0v));
    asm("v_permlane32_swap_b32 %0, %1" : "+v"(a1v), "+v"(b1v));
    asm("v_permlane32_swap_b32 %0, %1" : "+v"(a2v), "+v"(b2v));
    asm("v_permlane32_swap_b32 %0, %1" : "+v"(a3v), "+v"(b3v));
    union U { short8 s8; unsigned u[4]; };
    U p0, p1;
    p0.u[0] = a0v; p0.u[1] = a1v; p0.u[2] = b0v; p0.u[3] = b1v;
    p1.u[0] = a2v; p1.u[1] = a3v; p1.u[2] = b2v; p1.u[3] = b3v;

    acc0 = MFMA32(vc[0], p0.s8, acc0);
    acc0 = MFMA32(vc[1], p1.s8, acc0);
    acc1 = MFMA32(vc[2], p0.s8, acc1);
    acc1 = MFMA32(vc[3], p1.s8, acc1);
  };

  if (w < nkv) {
    loadKV(w, kA, vA);
    int kb = w;
    while (true) {
      step(kb, kA, vA, kB, vB); kb += 4; if (kb >= nkv) break;
      step(kb, kB, vB, kA, vA); kb += 4; if (kb >= nkv) break;
    }
  }

  lsum += __shfl_xor(lsum, 32, 64);
  if (hi == 0) lL[w8][q] = lsum;
#pragma unroll
  for (int r = 0; r < 16; ++r) {
    const int d = (r & 3) + 8 * (r >> 2) + 4 * hi;
    accL[w8][d][q]      = acc0[r];
    accL[w8][d + 32][q] = acc1[r];
  }
  __syncthreads();
  if (threadIdx.x < 64) {
    const int g2 = threadIdx.x >> 5;
    const int qq = threadIdx.x & 31;
    const float L = lL[g2 * 4 + 0][qq] + lL[g2 * 4 + 1][qq] +
                    lL[g2 * 4 + 2][qq] + lL[g2 * 4 + 3][qq];
    invL[g2][qq] = 1.f / L;
  }
  __syncthreads();
  {
    const int tid2 = threadIdx.x & 255;
#pragma unroll
    for (int pp = 0; pp < 8; ++pp) {
      const int qq = (tid2 >> 6) + 4 * pp;
      const int d  = tid2 & 63;
      const float v = accL[g * 4 + 0][d][qq] + accL[g * 4 + 1][d][qq] +
                      accL[g * 4 + 2][d][qq] + accL[g * 4 + 3][d][qq];
      out[(size_t)(b * T + qbase + qq) * HS + d] = v * invL[g][qq];
    }
  }
}

extern "C" void kernel_launch(void* const* d_in, const int* in_sizes, int n_in,
                              void* d_out, int out_size, void* d_ws, size_t ws_size,
                              hipStream_t stream) {
  const float* x  = (const float*)d_in[0];
  const float* Wq = (const float*)d_in[1];
  const float* bq = (const float*)d_in[2];
  const float* Wk = (const float*)d_in[3];
  const float* bk = (const float*)d_in[4];
  const float* Wv = (const float*)d_in[5];
  const float* bv = (const float*)d_in[6];
  float* out = (float*)d_out;

  unsigned short* Qf  = (unsigned short*)d_ws;
  unsigned short* Kf  = Qf + (size_t)B * T * HS;
  unsigned short* Vf  = Kf + (size_t)B * T * HS;
  unsigned short* Wtf = Vf + (size_t)B * T * HS;

  conv_w_kernel<<<48, 256, 0, stream>>>(Wq, Wk, Wv, Wtf);
  proj_kernel<<<B * T / 64, 512, 0, stream>>>(x, Wtf, bq, bk, bv, Qf, Kf, Vf);
  attn_kernel<<<B * 64, 512, 0, stream>>>(Qf, Kf, Vf, out);
}